// Round 12
// baseline (76.833 us; speedup 1.0000x reference)
//
#include <hip/hip_runtime.h>

namespace {
constexpr int kH = 192, kW = 640, kHW = kH * kW;
constexpr int kW4g = kW / 4;            // 160 granules per row
constexpr int kHW4 = kHW / 4;           // 30720 granules per plane
constexpr int kB = 2, kC = 64;          // batch, image channels
constexpr int kN0 = 40000, kC0 = 32;    // level0 points/channels
constexpr int kN1 = 20000, kC1 = 64;    // level1 points/channels
constexpr int kCL = 67;                 // C1 + 3
constexpr int kBHW = kB * kHW;
constexpr int kWin4 = 2 * kBHW / 4;
// k2 partition: scatter | precomp | gate(single-plane, 64 granules/block)
constexpr int kScatB = 469;   // ceil(120000/256)
constexpr int kGateB0 = 470;
constexpr int kGateB = kB * kHW4 / 64;  // 960
// kgym tile: 8 rows x 32 cols, halo 10 x 34
constexpr int kTH2 = 8, kTW2 = 32;
constexpr int kTilesX2 = kW / kTW2;         // 20
constexpr int kTilesY2 = kH / kTH2;         // 24
constexpr int kTilesPB = kTilesX2 * kTilesY2;  // 480
constexpr int kHaloH2 = kTH2 + 2, kHaloW2 = kTW2 + 2;  // 10 x 34
constexpr int kHaloN2 = kHaloH2 * kHaloW2;  // 340

typedef float vf4 __attribute__((ext_vector_type(4)));

// ---------------------------------------------------------------------------
// init: fill the two winner maps with -1.
// ---------------------------------------------------------------------------
__global__ __launch_bounds__(256) void kinit(int4* __restrict__ win4) {
  int i = blockIdx.x * 256 + threadIdx.x;
  if (i < kWin4) win4[i] = make_int4(-1, -1, -1, -1);
}

// ---------------------------------------------------------------------------
// K2 (heterogeneous, independent parts):
//  blocks [0,469): winner scatter (last-write-wins == max index wins)
//  block 469: LDS-staged fold: b'=W2@b0+b2; A1=Wsp^T@W2; M0=A1@W0;
//             sb_k=Wsp[:,k].b'; wsum_k=sum_c Wsp[c,k]
//  blocks [470,1430): gate -> SINGLE g plane. Block = 64 granules; 256 thr =
//   64 granules x 4 chunks of 16 ch; LDS-reduce the 4 partials (fixed order).
// ---------------------------------------------------------------------------
__global__ __launch_bounds__(256) void k2(
    const float* __restrict__ coor0, const float* __restrict__ coor1,
    int* __restrict__ win0, int* __restrict__ win1,
    const float* __restrict__ W0, const float* __restrict__ b0,
    const float* __restrict__ W2, const float* __restrict__ b2,
    const float* __restrict__ Wsp, float* __restrict__ M0,
    float* __restrict__ A1g, float* __restrict__ sb, float* __restrict__ wsum,
    const float* __restrict__ x_rgb, const float* __restrict__ W3,
    float* __restrict__ g) {
  __shared__ float W2s[kCL * kCL];
  __shared__ float W0s[kCL * 35];
  __shared__ float Wsps[kCL * 9];
  __shared__ float A1s[9 * kCL];
  __shared__ float bps[kCL];
  const int bid = blockIdx.x;
  const int t = threadIdx.x;
  if (bid >= kGateB0) {  // ---- gate ----
    __shared__ float4 part[4][64];
    const int gg = t & 63, q = t >> 6;
    const int gran = (bid - kGateB0) * 64 + gg;
    const int b = gran / kHW4;
    const int p4 = gran - b * kHW4;
    const float4* xr = (const float4*)(x_rgb + (size_t)b * kC * kHW) + p4;
    float4 acc = make_float4(0.f, 0.f, 0.f, 0.f);
#pragma unroll
    for (int cc = 0; cc < 16; ++cc) {
      const int c = q * 16 + cc;
      float wv = W3[c];
      float4 x4 = xr[(size_t)c * kHW4];
      acc.x += wv * x4.x;
      acc.y += wv * x4.y;
      acc.z += wv * x4.z;
      acc.w += wv * x4.w;
    }
    part[q][gg] = acc;
    __syncthreads();
    if (t < 64) {
      float4 p0 = part[0][t], p1 = part[1][t], p2 = part[2][t],
             p3 = part[3][t];
      float4 s;
      s.x = p0.x + p1.x + p2.x + p3.x;
      s.y = p0.y + p1.y + p2.y + p3.y;
      s.z = p0.z + p1.z + p2.z + p3.z;
      s.w = p0.w + p1.w + p2.w + p3.w;
      ((float4*)g)[(bid - kGateB0) * 64 + t] = s;
    }
    return;
  }
  if (bid < kScatB) {  // ---- scatter ----
    int idx = bid * 256 + t;
    const float* coor;
    int* win;
    int N;
    if (idx < kB * kN0) {
      coor = coor0; win = win0; N = kN0;
    } else {
      idx -= kB * kN0;
      if (idx >= kB * kN1) return;
      coor = coor1; win = win1; N = kN1;
    }
    int b = idx / N;
    float u = coor[(size_t)idx * 2 + 0];
    float v = coor[(size_t)idx * 2 + 1];
    u = fminf(fmaxf(u, 0.f), 1.f);
    v = fminf(fmaxf(v, 0.f), 1.f);
    int r = (int)(v * (float)kH);  // row from coor[:,1]
    int c = (int)(u * (float)kW);  // col from coor[:,0]
    if (r < kH && c < kW) {
      int n = idx - b * N;
      atomicMax(&win[b * kHW + r * kW + c], n);
    }
    return;
  }
  // ---- precomp (block 469, LDS-staged) ----
  for (int i = t; i < kCL * kCL; i += 256) W2s[i] = W2[i];
  for (int i = t; i < kCL * 35; i += 256) W0s[i] = W0[i];
  for (int i = t; i < kCL * 9; i += 256) Wsps[i] = Wsp[i];
  __syncthreads();
  if (t < kCL) {
    float s = b2[t];
    for (int j = 0; j < kCL; ++j) s += W2s[t * kCL + j] * b0[j];
    bps[t] = s;
  }
  for (int idx = t; idx < 9 * kCL; idx += 256) {
    int k = idx / kCL, j = idx - k * kCL;
    float s = 0.f;
    for (int c = 0; c < kCL; ++c) s += Wsps[c * 9 + k] * W2s[c * kCL + j];
    A1s[idx] = s;
    A1g[idx] = s;
  }
  __syncthreads();
  for (int idx = t; idx < 9 * 35; idx += 256) {
    int k = idx / 35, i = idx - k * 35;
    float s = 0.f;
    for (int j = 0; j < kCL; ++j) s += A1s[k * kCL + j] * W0s[j * 35 + i];
    M0[idx] = s;
  }
  if (t < 9) {
    float s = 0.f;
    for (int c = 0; c < kCL; ++c) s += Wsps[c * 9 + t] * bps[c];
    sb[t] = s;
  } else if (t >= 16 && t < 25) {
    int k = t - 16;
    float s = 0.f;
    for (int c = 0; c < kCL; ++c) s += Wsps[c * 9 + k];
    wsum[k] = s;
  }
}

// ---------------------------------------------------------------------------
// kgym: one 8x32 output tile per block (960 blocks).
// phase A (10x34 halo, ~1.33 px/thread): per-pixel tap projection
//   gv = b3 + g[pix];  y[k] = wsum[k]*gv + sb[k] + gathers  -> ylds (12 KB)
//   (out-of-image -> 0, identical to padded-plane semantics)
// phase B: att[px] = sigmoid(bsp + sum_{r,d} ylds[3r+d][lh+r][lw+d])
// phase C: out[c,px] = x[c,px]*att  -- x read once, granule-coalesced, NT.
// ---------------------------------------------------------------------------
__global__ __launch_bounds__(256) void kgym(
    const float* __restrict__ x_rgb, const float* __restrict__ g,
    const int* __restrict__ win0, const int* __restrict__ win1,
    const float* __restrict__ feat0, const float* __restrict__ vox0,
    const float* __restrict__ feat1, const float* __restrict__ vox1,
    const float* __restrict__ M0, const float* __restrict__ A1,
    const float* __restrict__ sb, const float* __restrict__ wsum,
    const float* __restrict__ b3, const float* __restrict__ bsp,
    float* __restrict__ out) {
  __shared__ float ylds[9][kHaloH2][kHaloW2];  // 12.2 KB
  __shared__ float att[256 + 8];
  const int t = threadIdx.x;
  const int tile = blockIdx.x;
  const int b = tile / kTilesPB;
  const int tr = tile - b * kTilesPB;
  const int ty = tr / kTilesX2, tx = tr - ty * kTilesX2;
  const int h0 = ty * kTH2, w0 = tx * kTW2;

  // ---- phase A ----
  for (int i = t; i < kHaloN2; i += 256) {
    const int hh = i / kHaloW2, ww = i - hh * kHaloW2;
    const int h = h0 + hh - 1, w = w0 + ww - 1;
    float y[9];
    if (h < 0 || h >= kH || w < 0 || w >= kW) {
#pragma unroll
      for (int k = 0; k < 9; ++k) y[k] = 0.f;
    } else {
      const int pix = b * kHW + h * kW + w;
      const float gv = b3[0] + g[pix];
#pragma unroll
      for (int k = 0; k < 9; ++k) y[k] = wsum[k] * gv + sb[k];
      const int w0i = win0[pix];
      if (w0i >= 0) {
        const float4* f0 =
            (const float4*)(feat0 + ((size_t)b * kN0 + w0i) * kC0);
#pragma unroll
        for (int i4 = 0; i4 < 8; ++i4) {
          float4 v = f0[i4];
#pragma unroll
          for (int k = 0; k < 9; ++k) {
            const float* m = M0 + k * 35 + i4 * 4;
            y[k] += m[0] * v.x + m[1] * v.y + m[2] * v.z + m[3] * v.w;
          }
        }
        const float* v0 = vox0 + ((size_t)b * kN0 + w0i) * 3;
#pragma unroll
        for (int ii = 0; ii < 3; ++ii) {
          float v = v0[ii];
#pragma unroll
          for (int k = 0; k < 9; ++k) y[k] += M0[k * 35 + kC0 + ii] * v;
        }
      }
      const int w1i = win1[pix];
      if (w1i >= 0) {
        const float4* f1 =
            (const float4*)(feat1 + ((size_t)b * kN1 + w1i) * kC1);
#pragma unroll
        for (int i4 = 0; i4 < 16; ++i4) {
          float4 v = f1[i4];
#pragma unroll
          for (int k = 0; k < 9; ++k) {
            const float* m = A1 + k * kCL + i4 * 4;
            y[k] += m[0] * v.x + m[1] * v.y + m[2] * v.z + m[3] * v.w;
          }
        }
        const float* v1 = vox1 + ((size_t)b * kN1 + w1i) * 3;
#pragma unroll
        for (int ii = 0; ii < 3; ++ii) {
          float v = v1[ii];
#pragma unroll
          for (int k = 0; k < 9; ++k) y[k] += A1[k * kCL + kC1 + ii] * v;
        }
      }
    }
#pragma unroll
    for (int k = 0; k < 9; ++k) ylds[k][hh][ww] = y[k];
  }
  __syncthreads();

  // ---- phase B ----
  {
    const int lh = t >> 5, lw = t & 31;
    float logit = bsp[0];
#pragma unroll
    for (int r = 0; r < 3; ++r) {
#pragma unroll
      for (int d = 0; d < 3; ++d) logit += ylds[3 * r + d][lh + r][lw + d];
    }
    att[t] = 1.f / (1.f + __expf(-logit));
  }
  __syncthreads();

  // ---- phase C ----
  const int gi = t & 63, cg = t >> 6;
  const int gr = gi >> 3, gc = gi & 7;
  const int gran = (h0 + gr) * kW4g + tx * 8 + gc;  // global float4 index
  const float4 a4 = *(const float4*)&att[gr * 32 + gc * 4];
  const vf4* xr = (const vf4*)(x_rgb + (size_t)b * kC * kHW) + gran;
  vf4* op = (vf4*)(out + (size_t)b * kC * kHW) + gran;
#pragma unroll
  for (int cc = 0; cc < 16; ++cc) {
    const int c = cg * 16 + cc;
    vf4 x4 = __builtin_nontemporal_load(xr + (size_t)c * kHW4);
    vf4 r4;
    r4.x = x4.x * a4.x;
    r4.y = x4.y * a4.y;
    r4.z = x4.z * a4.z;
    r4.w = x4.w * a4.w;
    __builtin_nontemporal_store(r4, op + (size_t)c * kHW4);
  }
}

}  // namespace

extern "C" void kernel_launch(void* const* d_in, const int* in_sizes, int n_in,
                              void* d_out, int out_size, void* d_ws,
                              size_t ws_size, hipStream_t stream) {
  const float* x_rgb = (const float*)d_in[0];
  const float* feat0 = (const float*)d_in[1];
  const float* coor0 = (const float*)d_in[2];
  const float* vox0 = (const float*)d_in[3];
  const float* feat1 = (const float*)d_in[4];
  const float* coor1 = (const float*)d_in[5];
  const float* vox1 = (const float*)d_in[6];
  const float* W0 = (const float*)d_in[7];
  const float* b0 = (const float*)d_in[8];
  const float* W2 = (const float*)d_in[9];
  const float* b2 = (const float*)d_in[10];
  const float* W3 = (const float*)d_in[11];
  const float* b3 = (const float*)d_in[12];
  const float* Wsp = (const float*)d_in[13];
  const float* bsp = (const float*)d_in[14];
  float* out = (float*)d_out;

  // workspace: g[BHW] | win0[BHW] | win1[BHW] | M0 | A1 | sb | wsum
  float* g = (float*)d_ws;
  int* win0 = (int*)(g + (size_t)kBHW);
  int* win1 = win0 + (size_t)kBHW;
  float* M0 = (float*)(win1 + (size_t)kBHW);
  float* A1 = M0 + 9 * 35;
  float* sb = A1 + 9 * kCL;
  float* wsum = sb + 9;

  kinit<<<(kWin4 + 255) / 256, 256, 0, stream>>>((int4*)win0);
  k2<<<kGateB0 + kGateB, 256, 0, stream>>>(coor0, coor1, win0, win1, W0, b0,
                                           W2, b2, Wsp, M0, A1, sb, wsum,
                                           x_rgb, W3, g);
  kgym<<<kB * kTilesPB, 256, 0, stream>>>(x_rgb, g, win0, win1, feat0, vox0,
                                          feat1, vox1, M0, A1, sb, wsum, b3,
                                          bsp, out);
}